// Round 1
// baseline (552.580 us; speedup 1.0000x reference)
//
#include <hip/hip_runtime.h>
#include <hip/hip_bf16.h>

// ---------------------------------------------------------------------------
// QuantizedLinear: out[M,N] = (x[M,K] @ (Wq[N,K]*s[N,1]).T) + b[N]
// Strategy: Wq int8-valued -> bf16 EXACT; x -> bf16 (RN). MFMA bf16 GEMM on
// unscaled weights; scale+bias fused in fp32 epilogue.
// M=4096 K=4096 N=11008 (all tile-divisible: 128|M, 128|N, 64|K).
// ---------------------------------------------------------------------------

typedef __attribute__((ext_vector_type(8))) short bf16x8;   // 8 bf16 = 4 VGPR
typedef __attribute__((ext_vector_type(4))) float f32x4;
typedef __attribute__((ext_vector_type(4))) unsigned int u32x4;

// ---- fp32 -> bf16 (round-to-nearest-even), 8 elems/thread/iter -------------
__device__ static inline unsigned int bf16rn(unsigned int u) {
    return (u + 0x7FFFu + ((u >> 16) & 1u)) >> 16;
}
__device__ static inline unsigned int pack2(unsigned int lo, unsigned int hi) {
    return bf16rn(lo) | (bf16rn(hi) << 16);
}

__global__ void f32_to_bf16_kernel(const float* __restrict__ in,
                                   unsigned int* __restrict__ out, long n8) {
    const long stride = (long)gridDim.x * blockDim.x;
    for (long i = (long)blockIdx.x * blockDim.x + threadIdx.x; i < n8; i += stride) {
        u32x4 a = reinterpret_cast<const u32x4*>(in)[i * 2];
        u32x4 b = reinterpret_cast<const u32x4*>(in)[i * 2 + 1];
        u32x4 o;
        o.x = pack2(a.x, a.y);
        o.y = pack2(a.z, a.w);
        o.z = pack2(b.x, b.y);
        o.w = pack2(b.z, b.w);
        reinterpret_cast<u32x4*>(out)[i] = o;
    }
}

// ---- main GEMM: m97 structure (128x128x64, 4 waves, global_load_lds x16) ---
#define BM 128
#define BN 128
#define BK 64

__device__ static inline void gload_lds16(const void* g, void* l) {
    __builtin_amdgcn_global_load_lds(
        (const __attribute__((address_space(1))) void*)g,
        (__attribute__((address_space(3))) void*)l, 16, 0, 0);
}

__global__ void qlinear_gemm_bf16(const unsigned short* __restrict__ A,  // [M,K] bf16
                                  const unsigned short* __restrict__ B,  // [N,K] bf16
                                  const float* __restrict__ scales,      // [N]
                                  const float* __restrict__ bias,        // [N]
                                  float* __restrict__ C,                 // [M,N]
                                  int M, int N, int K) {
    __shared__ unsigned short Asm[BM * BK];  // [128][64]
    __shared__ unsigned short Bsm[BN * BK];

    const int tid  = threadIdx.x;
    const int lane = tid & 63;
    const int wid  = tid >> 6;
    const int wr   = wid >> 1;   // wave row (0..1) -> 64-row slab
    const int wc   = wid & 1;    // wave col (0..1) -> 64-col slab

    const int brow = blockIdx.y;  // M tile
    const int bcol = blockIdx.x;  // N tile

    f32x4 acc[4][4] = {};

    // staging map: thread t -> row r0 = t/8 (+j*32), col c0 = (t%8)*8 elems
    const int r0 = tid >> 3;
    const int c0 = (tid & 7) * 8;

    const unsigned short* Ag = A + (long)(brow * BM) * K;
    const unsigned short* Bg = B + (long)(bcol * BN) * K;

    for (int k0 = 0; k0 < K; k0 += BK) {
#pragma unroll
        for (int j = 0; j < 4; ++j) {
            const int r = j * 32 + r0;
            gload_lds16(Ag + (long)r * K + k0 + c0, &Asm[r * BK + c0]);
        }
#pragma unroll
        for (int j = 0; j < 4; ++j) {
            const int r = j * 32 + r0;
            gload_lds16(Bg + (long)r * K + k0 + c0, &Bsm[r * BK + c0]);
        }
        __syncthreads();

#pragma unroll
        for (int kk = 0; kk < 2; ++kk) {
            const int koff = kk * 32 + (lane >> 4) * 8;
            bf16x8 a[4], b[4];
#pragma unroll
            for (int mi = 0; mi < 4; ++mi) {
                const int m = wr * 64 + mi * 16 + (lane & 15);
                a[mi] = *reinterpret_cast<const bf16x8*>(&Asm[m * BK + koff]);
            }
#pragma unroll
            for (int ni = 0; ni < 4; ++ni) {
                const int n = wc * 64 + ni * 16 + (lane & 15);
                b[ni] = *reinterpret_cast<const bf16x8*>(&Bsm[n * BK + koff]);
            }
#pragma unroll
            for (int mi = 0; mi < 4; ++mi)
#pragma unroll
                for (int ni = 0; ni < 4; ++ni)
                    acc[mi][ni] = __builtin_amdgcn_mfma_f32_16x16x32_bf16(
                        a[mi], b[ni], acc[mi][ni], 0, 0, 0);
        }
        __syncthreads();
    }

    // epilogue: C/D layout (16x16x32): col = lane&15, row = (lane>>4)*4 + j
    const int lc = lane & 15;
    const int lr = (lane >> 4) * 4;
#pragma unroll
    for (int ni = 0; ni < 4; ++ni) {
        const int n = bcol * BN + wc * 64 + ni * 16 + lc;
        const float s  = scales[n];
        const float bz = bias[n];
#pragma unroll
        for (int mi = 0; mi < 4; ++mi) {
            const int mbase = brow * BM + wr * 64 + mi * 16 + lr;
#pragma unroll
            for (int j = 0; j < 4; ++j) {
                C[(long)(mbase + j) * N + n] = fmaf(acc[mi][ni][j], s, bz);
            }
        }
    }
}

// ---- fallback (ws too small): plain fp32 tiled GEMM, correctness insurance -
__global__ void qlinear_fallback(const float* __restrict__ A,
                                 const float* __restrict__ B,
                                 const float* __restrict__ scales,
                                 const float* __restrict__ bias,
                                 float* __restrict__ C, int M, int N, int K) {
    __shared__ float As[16][17], Bs[16][17];
    const int tx = threadIdx.x, ty = threadIdx.y;
    const int row = blockIdx.y * 16 + ty;
    const int col = blockIdx.x * 16 + tx;
    float acc = 0.f;
    for (int k0 = 0; k0 < K; k0 += 16) {
        As[ty][tx] = A[(long)row * K + k0 + tx];
        Bs[ty][tx] = B[(long)(blockIdx.x * 16 + ty) * K + k0 + tx];
        __syncthreads();
#pragma unroll
        for (int kk = 0; kk < 16; ++kk) acc += As[ty][kk] * Bs[tx][kk];
        __syncthreads();
    }
    C[(long)row * N + col] = fmaf(acc, scales[col], bias[col]);
}

extern "C" void kernel_launch(void* const* d_in, const int* in_sizes, int n_in,
                              void* d_out, int out_size, void* d_ws, size_t ws_size,
                              hipStream_t stream) {
    const float* x      = (const float*)d_in[0];
    const float* w      = (const float*)d_in[1];
    const float* scales = (const float*)d_in[2];
    const float* bias   = (const float*)d_in[3];
    float* out = (float*)d_out;

    const int N = in_sizes[2];                 // 11008
    const int K = (int)((long)in_sizes[1] / N); // 4096
    const int M = (int)((long)in_sizes[0] / K); // 4096

    const size_t need = ((size_t)M * K + (size_t)N * K) * sizeof(unsigned short);
    if (ws_size >= need && (M % BM) == 0 && (N % BN) == 0 && (K % BK) == 0) {
        unsigned short* xb = (unsigned short*)d_ws;
        unsigned short* wb = xb + (size_t)M * K;

        const long n8x = (long)M * K / 8;
        const long n8w = (long)N * K / 8;
        f32_to_bf16_kernel<<<2048, 256, 0, stream>>>(x, (unsigned int*)xb, n8x);
        f32_to_bf16_kernel<<<2048, 256, 0, stream>>>(w, (unsigned int*)wb, n8w);

        dim3 grid(N / BN, M / BM);
        qlinear_gemm_bf16<<<grid, 256, 0, stream>>>(xb, wb, scales, bias, out, M, N, K);
    } else {
        dim3 grid(N / 16, M / 16), blk(16, 16);
        qlinear_fallback<<<grid, blk, 0, stream>>>(x, w, scales, bias, out, M, N, K);
    }
}

// Round 2
// 455.780 us; speedup vs baseline: 1.2124x; 1.2124x over previous
//
#include <hip/hip_runtime.h>
#include <hip/hip_bf16.h>

// ---------------------------------------------------------------------------
// QuantizedLinear: out[M,N] = (x[M,K] @ (Wq[N,K]*s[N,1]).T) + b[N]
// Wq int8-valued -> bf16 EXACT; x -> bf16 RNE. bf16 MFMA GEMM, scale+bias in
// fp32 epilogue. M=4096 K=4096 N=11008.
// Round 2: 256x256 8-phase schedule (T1 XCD swizzle + T2 LDS XOR swizzle +
// T3/T4 counted vmcnt + T5 setprio), K-half staging slots.
// ---------------------------------------------------------------------------

typedef __attribute__((ext_vector_type(8))) short bf16x8;   // 8 bf16 = 4 VGPR
typedef __attribute__((ext_vector_type(4))) float f32x4;
typedef __attribute__((ext_vector_type(4))) unsigned int u32x4;

// ---- fp32 -> bf16 (round-to-nearest-even), 8 elems/thread/iter -------------
__device__ static inline unsigned int bf16rn(unsigned int u) {
    return (u + 0x7FFFu + ((u >> 16) & 1u)) >> 16;
}
__device__ static inline unsigned int pack2(unsigned int lo, unsigned int hi) {
    return bf16rn(lo) | (bf16rn(hi) << 16);
}

__global__ void f32_to_bf16_kernel(const float* __restrict__ in,
                                   unsigned int* __restrict__ out, long n8) {
    const long stride = (long)gridDim.x * blockDim.x;
    for (long i = (long)blockIdx.x * blockDim.x + threadIdx.x; i < n8; i += stride) {
        u32x4 a = reinterpret_cast<const u32x4*>(in)[i * 2];
        u32x4 b = reinterpret_cast<const u32x4*>(in)[i * 2 + 1];
        u32x4 o;
        o.x = pack2(a.x, a.y);
        o.y = pack2(a.z, a.w);
        o.z = pack2(b.x, b.y);
        o.w = pack2(b.z, b.w);
        reinterpret_cast<u32x4*>(out)[i] = o;
    }
}

// ---------------------------------------------------------------------------
// 256x256x64 8-phase GEMM, 512 threads (8 waves, 2M x 4N).
// LDS 128 KiB: 8 regions of 16 KiB: [mat A/B][dbuf][K-half] x [256 rows][32 el]
// Staging slot = one (mat, K-half): 256x32 bf16 = 16 KiB = 2 gload16/thread.
// Per K-tile: 4 phases; phase issues 1 slot of tile t+1; vmcnt(4) mid + end.
// LDS read swizzle: 16B slot index ^= (row>>2)&3  (bijective, ~2-way banks);
// staging pre-swizzles the GLOBAL source, LDS dest stays linear (rule #21).
// ---------------------------------------------------------------------------
#define BM 256
#define BN 256
#define BK 64
#define KH 32

#define GLOAD16(src, dst) __builtin_amdgcn_global_load_lds( \
    (const __attribute__((address_space(1))) void*)(src),   \
    (__attribute__((address_space(3))) void*)(dst), 16, 0, 0)

#define FENCE() asm volatile("" ::: "memory")
#define BAR()  do { FENCE(); __builtin_amdgcn_s_barrier(); FENCE(); } while (0)
#define WAIT_LGKM0() asm volatile("s_waitcnt lgkmcnt(0)" ::: "memory")
#define WAIT_VM(n) asm volatile("s_waitcnt vmcnt(" #n ")" ::: "memory")

__global__ __launch_bounds__(512, 2)
void qlinear_gemm_8phase(const unsigned short* __restrict__ A,  // [M,K] bf16
                         const unsigned short* __restrict__ B,  // [N,K] bf16
                         const float* __restrict__ scales,
                         const float* __restrict__ bias,
                         float* __restrict__ C,                 // [M,N] f32
                         int M, int N, int K, int nbx) {
    __shared__ __align__(128) char smem[131072];

    const int tid  = threadIdx.x;
    const int lane = tid & 63;
    const int wid  = tid >> 6;
    const int wr   = wid >> 2;   // 0..1 -> 128-row slab
    const int wc   = wid & 3;    // 0..3 -> 64-col slab

    // T1: bijective XCD swizzle (m204 formula)
    const int nwg = gridDim.x;
    const int q = nwg >> 3, r = nwg & 7;
    const int xcd = blockIdx.x & 7, boff_ = blockIdx.x >> 3;
    const int swz = (xcd < r ? xcd * (q + 1) : r * (q + 1) + (xcd - r) * q) + boff_;
    const int bcol = swz % nbx;
    const int brow = swz / nbx;

    const unsigned short* Ag = A + (size_t)brow * BM * K;
    const unsigned short* Bg = B + (size_t)bcol * BN * K;

    // ---- staging geometry (per thread, 2 loads per slot) ----
    // load j covers LDS rows [wid*32 + j*16, +16); lane -> row wid*32+j*16+(lane>>2),
    // 16B chunk (lane&3). LDS dest linear; global source pre-swizzled.
    const int srow = wid * 32 + (lane >> 2);
    const int sb   = (lane & 3) << 4;
    const int ssw  = sb ^ (((srow >> 2) & 3) << 4);   // same for j=0,1 (row+16)
    const int sdst = srow * 64 + sb;

    // ---- read geometry ----
    const int ra = wr * 128 + (lane & 15);
    const int rb = wc * 64  + (lane & 15);
    const int kslot = (lane >> 4) << 4;               // 16B chunk within K-half
    const int aoff = ra * 64 + (kslot ^ (((ra >> 2) & 3) << 4));
    const int boff = rb * 64 + (kslot ^ (((rb >> 2) & 3) << 4));

    f32x4 acc[8][4] = {};
    bf16x8 af[4], bfr[4];

    const int NT = K / BK;

    auto issue = [&](int mat, int d, int kh, int k0) {
        const unsigned short* G = mat ? Bg : Ag;
        const char* g0 = (const char*)G + ((size_t)srow * K + k0 + kh * KH) * 2 + ssw;
        char* l0 = smem + (((mat << 2) | (d << 1) | kh) << 14) + sdst;
        GLOAD16(g0, l0);
        GLOAD16(g0 + (size_t)16 * K * 2, l0 + 1024);   // j=1: +16 rows
    };
    auto readA = [&](int c, int kk, int mih) {         // mi = mih*4 .. +3
        const char* p = smem + (((c << 1) | kk) << 14) + aoff + mih * 4096;
        af[0] = *(const bf16x8*)(p);
        af[1] = *(const bf16x8*)(p + 1024);
        af[2] = *(const bf16x8*)(p + 2048);
        af[3] = *(const bf16x8*)(p + 3072);
    };
    auto readB = [&](int c, int kk) {
        const char* p = smem + ((4 | (c << 1) | kk) << 14) + boff;
        bfr[0] = *(const bf16x8*)(p);
        bfr[1] = *(const bf16x8*)(p + 1024);
        bfr[2] = *(const bf16x8*)(p + 2048);
        bfr[3] = *(const bf16x8*)(p + 3072);
    };
    auto mfma16 = [&](int mih) {
#pragma unroll
        for (int i = 0; i < 4; ++i)
#pragma unroll
            for (int n = 0; n < 4; ++n)
                acc[mih * 4 + i][n] = __builtin_amdgcn_mfma_f32_16x16x32_bf16(
                    af[i], bfr[n], acc[mih * 4 + i][n], 0, 0, 0);
    };

    // ---- prologue: stage tile 0 (slots: Akh0, Bkh0, Akh1, Bkh1) ----
    issue(0, 0, 0, 0);
    issue(1, 0, 0, 0);
    issue(0, 0, 1, 0);
    issue(1, 0, 1, 0);
    WAIT_VM(4);                       // Akh0,Bkh0 landed; Akh1,Bkh1 in flight
    __builtin_amdgcn_s_barrier();

    // ---- main loop: invariant at top: S(t,kh1-slots) in flight (4 loads) ----
    for (int t = 0; t < NT - 1; ++t) {
        const int c = t & 1;
        const int k1 = (t + 1) * BK;
        // P0: issue A-kh0(t+1) | read kh0 frags | MFMA mi0-3
        issue(0, 1 - c, 0, k1);
        readA(c, 0, 0); readB(c, 0);
        BAR(); WAIT_LGKM0();
        __builtin_amdgcn_s_setprio(1); mfma16(0); __builtin_amdgcn_s_setprio(0);
        BAR();
        // P1: issue B-kh0(t+1) | read A kh0 mi4-7 | MFMA mi4-7
        issue(1, 1 - c, 0, k1);
        readA(c, 0, 1);
        BAR(); WAIT_LGKM0();
        __builtin_amdgcn_s_setprio(1); mfma16(1); __builtin_amdgcn_s_setprio(0);
        WAIT_VM(4);                   // retire S(t,kh1) slots; keep t+1 kh0 in flight
        BAR();
        // P2: issue A-kh1(t+1) | read kh1 frags | MFMA mi0-3
        issue(0, 1 - c, 1, k1);
        readA(c, 1, 0); readB(c, 1);
        BAR(); WAIT_LGKM0();
        __builtin_amdgcn_s_setprio(1); mfma16(0); __builtin_amdgcn_s_setprio(0);
        BAR();
        // P3: issue B-kh1(t+1) | read A kh1 mi4-7 | MFMA mi4-7
        issue(1, 1 - c, 1, k1);
        readA(c, 1, 1);
        BAR(); WAIT_LGKM0();
        __builtin_amdgcn_s_setprio(1); mfma16(1); __builtin_amdgcn_s_setprio(0);
        WAIT_VM(4);                   // retire S(t+1,kh0); keep S(t+1,kh1) in flight
        BAR();
    }

    // ---- epilogue tile NT-1 (no prefetch; one vmcnt(0) allowed here) ----
    {
        const int c = (NT - 1) & 1;
        readA(c, 0, 0); readB(c, 0);
        BAR(); WAIT_LGKM0();
        __builtin_amdgcn_s_setprio(1); mfma16(0); __builtin_amdgcn_s_setprio(0);
        BAR();
        readA(c, 0, 1);
        BAR(); WAIT_LGKM0();
        __builtin_amdgcn_s_setprio(1); mfma16(1); __builtin_amdgcn_s_setprio(0);
        WAIT_VM(0);                   // kh1 slots landed
        BAR();
        readA(c, 1, 0); readB(c, 1);
        BAR(); WAIT_LGKM0();
        __builtin_amdgcn_s_setprio(1); mfma16(0); __builtin_amdgcn_s_setprio(0);
        BAR();
        readA(c, 1, 1);
        WAIT_LGKM0();
        mfma16(1);
    }

    // ---- C write: col = lane&15 (n), row = (lane>>4)*4 + j (m) ----
    const int lc = lane & 15;
    const int lr4 = (lane >> 4) * 4;
    const int nbase0 = bcol * BN + wc * 64 + lc;
    const int mbase0 = brow * BM + wr * 128 + lr4;
#pragma unroll
    for (int ni = 0; ni < 4; ++ni) {
        const int n = nbase0 + ni * 16;
        const float s  = scales[n];
        const float bz = bias[n];
#pragma unroll
        for (int mi = 0; mi < 8; ++mi) {
            const int mb = mbase0 + mi * 16;
#pragma unroll
            for (int j = 0; j < 4; ++j) {
                C[(size_t)(mb + j) * N + n] = fmaf(acc[mi][ni][j], s, bz);
            }
        }
    }
}

// ---------------------------------------------------------------------------
// Fallback 1: round-1 128x128 m97-structure kernel (if 256-divisibility fails)
// ---------------------------------------------------------------------------
#define FBM 128
#define FBN 128
#define FBK 64

__global__ void qlinear_gemm_bf16(const unsigned short* __restrict__ A,
                                  const unsigned short* __restrict__ B,
                                  const float* __restrict__ scales,
                                  const float* __restrict__ bias,
                                  float* __restrict__ C,
                                  int M, int N, int K) {
    __shared__ unsigned short Asm[FBM * FBK];
    __shared__ unsigned short Bsm[FBN * FBK];

    const int tid  = threadIdx.x;
    const int lane = tid & 63;
    const int wid  = tid >> 6;
    const int wr   = wid >> 1;
    const int wc   = wid & 1;

    const int brow = blockIdx.y;
    const int bcol = blockIdx.x;

    f32x4 acc[4][4] = {};

    const int r0 = tid >> 3;
    const int c0 = (tid & 7) * 8;

    const unsigned short* Ag = A + (long)(brow * FBM) * K;
    const unsigned short* Bg = B + (long)(bcol * FBN) * K;

    for (int k0 = 0; k0 < K; k0 += FBK) {
#pragma unroll
        for (int j = 0; j < 4; ++j) {
            const int rr = j * 32 + r0;
            GLOAD16(Ag + (long)rr * K + k0 + c0, &Asm[rr * FBK + c0]);
        }
#pragma unroll
        for (int j = 0; j < 4; ++j) {
            const int rr = j * 32 + r0;
            GLOAD16(Bg + (long)rr * K + k0 + c0, &Bsm[rr * FBK + c0]);
        }
        __syncthreads();

#pragma unroll
        for (int kk = 0; kk < 2; ++kk) {
            const int koff = kk * 32 + (lane >> 4) * 8;
            bf16x8 a[4], b[4];
#pragma unroll
            for (int mi = 0; mi < 4; ++mi) {
                const int m = wr * 64 + mi * 16 + (lane & 15);
                a[mi] = *reinterpret_cast<const bf16x8*>(&Asm[m * FBK + koff]);
            }
#pragma unroll
            for (int ni = 0; ni < 4; ++ni) {
                const int n = wc * 64 + ni * 16 + (lane & 15);
                b[ni] = *reinterpret_cast<const bf16x8*>(&Bsm[n * FBK + koff]);
            }
#pragma unroll
            for (int mi = 0; mi < 4; ++mi)
#pragma unroll
                for (int ni = 0; ni < 4; ++ni)
                    acc[mi][ni] = __builtin_amdgcn_mfma_f32_16x16x32_bf16(
                        a[mi], b[ni], acc[mi][ni], 0, 0, 0);
        }
        __syncthreads();
    }

    const int lc = lane & 15;
    const int lr = (lane >> 4) * 4;
#pragma unroll
    for (int ni = 0; ni < 4; ++ni) {
        const int n = bcol * FBN + wc * 64 + ni * 16 + lc;
        const float s  = scales[n];
        const float bz = bias[n];
#pragma unroll
        for (int mi = 0; mi < 4; ++mi) {
            const int mbase = brow * FBM + wr * 64 + mi * 16 + lr;
#pragma unroll
            for (int j = 0; j < 4; ++j) {
                C[(long)(mbase + j) * N + n] = fmaf(acc[mi][ni][j], s, bz);
            }
        }
    }
}

// ---- Fallback 2: plain fp32 tiled GEMM, correctness insurance --------------
__global__ void qlinear_fallback(const float* __restrict__ A,
                                 const float* __restrict__ B,
                                 const float* __restrict__ scales,
                                 const float* __restrict__ bias,
                                 float* __restrict__ C, int M, int N, int K) {
    __shared__ float As[16][17], Bs[16][17];
    const int tx = threadIdx.x, ty = threadIdx.y;
    const int row = blockIdx.y * 16 + ty;
    const int col = blockIdx.x * 16 + tx;
    float acc = 0.f;
    for (int k0 = 0; k0 < K; k0 += 16) {
        As[ty][tx] = A[(long)row * K + k0 + tx];
        Bs[ty][tx] = B[(long)(blockIdx.x * 16 + ty) * K + k0 + tx];
        __syncthreads();
#pragma unroll
        for (int kk = 0; kk < 16; ++kk) acc += As[ty][kk] * Bs[tx][kk];
        __syncthreads();
    }
    C[(long)row * N + col] = fmaf(acc, scales[col], bias[col]);
}

extern "C" void kernel_launch(void* const* d_in, const int* in_sizes, int n_in,
                              void* d_out, int out_size, void* d_ws, size_t ws_size,
                              hipStream_t stream) {
    const float* x      = (const float*)d_in[0];
    const float* w      = (const float*)d_in[1];
    const float* scales = (const float*)d_in[2];
    const float* bias   = (const float*)d_in[3];
    float* out = (float*)d_out;

    const int N = in_sizes[2];                  // 11008
    const int K = (int)((long)in_sizes[1] / N); // 4096
    const int M = (int)((long)in_sizes[0] / K); // 4096

    const size_t need = ((size_t)M * K + (size_t)N * K) * sizeof(unsigned short);
    const bool ws_ok = (ws_size >= need);

    if (ws_ok && (M % 256) == 0 && (N % 256) == 0 && (K % 64) == 0 && (K / 64) >= 2) {
        unsigned short* xb = (unsigned short*)d_ws;
        unsigned short* wb = xb + (size_t)M * K;
        f32_to_bf16_kernel<<<2048, 256, 0, stream>>>(x, (unsigned int*)xb, (long)M * K / 8);
        f32_to_bf16_kernel<<<2048, 256, 0, stream>>>(w, (unsigned int*)wb, (long)N * K / 8);
        const int nbx = N / 256;
        const int nwg = nbx * (M / 256);
        qlinear_gemm_8phase<<<nwg, 512, 0, stream>>>(xb, wb, scales, bias, out, M, N, K, nbx);
    } else if (ws_ok && (M % 128) == 0 && (N % 128) == 0 && (K % 64) == 0) {
        unsigned short* xb = (unsigned short*)d_ws;
        unsigned short* wb = xb + (size_t)M * K;
        f32_to_bf16_kernel<<<2048, 256, 0, stream>>>(x, (unsigned int*)xb, (long)M * K / 8);
        f32_to_bf16_kernel<<<2048, 256, 0, stream>>>(w, (unsigned int*)wb, (long)N * K / 8);
        dim3 grid(N / FBN, M / FBM);
        qlinear_gemm_bf16<<<grid, 256, 0, stream>>>(xb, wb, scales, bias, out, M, N, K);
    } else {
        dim3 grid(N / 16, M / 16), blk(16, 16);
        qlinear_fallback<<<grid, blk, 0, stream>>>(x, w, scales, bias, out, M, N, K);
    }
}

// Round 3
// 446.729 us; speedup vs baseline: 1.2369x; 1.0203x over previous
//
#include <hip/hip_runtime.h>
#include <hip/hip_bf16.h>

// ---------------------------------------------------------------------------
// QuantizedLinear: out[M,N] = (x[M,K] @ (Wq[N,K]*s[N,1]).T) + b[N]
// Wq int8-valued -> bf16 EXACT; x -> bf16 RNE. bf16 MFMA GEMM, scale+bias in
// fp32 epilogue. M=4096 K=4096 N=11008.
// Round 3: 2-syncs-per-K-tile schedule. R2's 8-barrier lockstep serialized
// LDS-read drain (2370 cyc/CU/K-tile) against MFMA (2061 cyc) -> 5861 cyc
// measured. Now: reads issue ahead of MFMA clusters between counted-vmcnt
// syncs; compiler emits fine lgkmcnt; raw s_barrier (no vmcnt(0) drain).
// Swizzle: m201 transplant (flip bit5 with row-bit3; 32B pairs preserved).
// ---------------------------------------------------------------------------

typedef __attribute__((ext_vector_type(8))) short bf16x8;   // 8 bf16 = 4 VGPR
typedef __attribute__((ext_vector_type(4))) float f32x4;
typedef __attribute__((ext_vector_type(4))) unsigned int u32x4;

// ---- fp32 -> bf16 (round-to-nearest-even), 8 elems/thread/iter -------------
__device__ static inline unsigned int bf16rn(unsigned int u) {
    return (u + 0x7FFFu + ((u >> 16) & 1u)) >> 16;
}
__device__ static inline unsigned int pack2(unsigned int lo, unsigned int hi) {
    return bf16rn(lo) | (bf16rn(hi) << 16);
}

__global__ void f32_to_bf16_kernel(const float* __restrict__ in,
                                   unsigned int* __restrict__ out, long n8) {
    const long stride = (long)gridDim.x * blockDim.x;
    for (long i = (long)blockIdx.x * blockDim.x + threadIdx.x; i < n8; i += stride) {
        u32x4 a = reinterpret_cast<const u32x4*>(in)[i * 2];
        u32x4 b = reinterpret_cast<const u32x4*>(in)[i * 2 + 1];
        u32x4 o;
        o.x = pack2(a.x, a.y);
        o.y = pack2(a.z, a.w);
        o.z = pack2(b.x, b.y);
        o.w = pack2(b.z, b.w);
        reinterpret_cast<u32x4*>(out)[i] = o;
    }
}

// ---------------------------------------------------------------------------
// 256x256x64 GEMM, 512 threads (8 waves, 2M x 4N), LDS 128 KiB:
// 8 regions of 16 KiB: [mat A/B][dbuf][K-half] x [256 rows][32 el (64 B)].
// Slot = (mat, K-half) = 16 KiB = 2 gload16/thread. K-half slots stream with
// vmcnt(4) at the 2 per-tile syncs; 4 loads always in flight.
// ---------------------------------------------------------------------------
#define BM 256
#define BN 256
#define BK 64
#define KH 32

#define GLOAD16(src, dst) __builtin_amdgcn_global_load_lds( \
    (const __attribute__((address_space(1))) void*)(src),   \
    (__attribute__((address_space(3))) void*)(dst), 16, 0, 0)

#define FENCE() asm volatile("" ::: "memory")
#define WAIT_VM(n) asm volatile("s_waitcnt vmcnt(" #n ")" ::: "memory")
// counted-vmcnt sync point: per-wave vm wait, then cross-wave publish
#define SYNC_VM(n) do { FENCE(); WAIT_VM(n); FENCE(); \
    __builtin_amdgcn_s_barrier(); FENCE(); } while (0)

__global__ __launch_bounds__(512, 2)
void qlinear_gemm_v3(const unsigned short* __restrict__ A,  // [M,K] bf16
                     const unsigned short* __restrict__ B,  // [N,K] bf16
                     const float* __restrict__ scales,
                     const float* __restrict__ bias,
                     float* __restrict__ C,                 // [M,N] f32
                     int M, int N, int K, int nbx) {
    __shared__ __align__(128) char smem[131072];

    const int tid  = threadIdx.x;
    const int lane = tid & 63;
    const int wid  = tid >> 6;
    const int wr   = wid >> 2;   // 0..1 -> 128-row slab of C
    const int wc   = wid & 3;    // 0..3 -> 64-col slab of C

    // T1: bijective XCD swizzle (m204)
    const int nwg = gridDim.x;
    const int q = nwg >> 3, r = nwg & 7;
    const int xcd = blockIdx.x & 7, boff_ = blockIdx.x >> 3;
    const int swz = (xcd < r ? xcd * (q + 1) : r * (q + 1) + (xcd - r) * q) + boff_;
    const int bcol = swz % nbx;
    const int brow = swz / nbx;

    const unsigned short* Ag = A + (size_t)brow * BM * K;
    const unsigned short* Bg = B + (size_t)bcol * BN * K;

    // ---- staging geometry: lane -> LDS linear (srow, 16B chunk sb);
    // global source pre-swizzled by the read swizzle's inverse (involution).
    const int srow = wid * 32 + (lane >> 2);
    const int sb   = (lane & 3) << 4;
    const int ssw  = sb ^ (((srow >> 3) & 1) << 5);   // bit5 ^= row bit3
    const int sdst = srow * 64 + sb;                  // == wave base + lane*16

    // ---- read geometry (mask constant across +16/+32/+48/+64 row steps) ----
    const int ra = wr * 128 + (lane & 15);
    const int rb = wc * 64  + (lane & 15);
    const int kslot = (lane >> 4) << 4;
    const int aoff = ra * 64 + (kslot ^ (((ra >> 3) & 1) << 5));
    const int boff = rb * 64 + (kslot ^ (((rb >> 3) & 1) << 5));

    f32x4 acc[8][4] = {};
    bf16x8 af0[4], af1[4], bf0[4];

    const int NT = K / BK;

    auto issue = [&](int mat, int d, int kh, int k0) {
        const unsigned short* G = mat ? Bg : Ag;
        const char* g0 = (const char*)G + ((size_t)srow * K + k0 + kh * KH) * 2 + ssw;
        char* l0 = smem + (((mat << 2) | (d << 1) | kh) << 14) + sdst;
        GLOAD16(g0, l0);
        GLOAD16(g0 + (size_t)16 * K * 2, l0 + 1024);   // +16 rows
    };
    auto rdA = [&](int c, int kh, int mih, bf16x8* d) {
        const char* p = smem + (((c << 1) | kh) << 14) + aoff + mih * 4096;
        d[0] = *(const bf16x8*)(p);
        d[1] = *(const bf16x8*)(p + 1024);
        d[2] = *(const bf16x8*)(p + 2048);
        d[3] = *(const bf16x8*)(p + 3072);
    };
    auto rdB = [&](int c, int kh, bf16x8* d) {
        const char* p = smem + ((4 | (c << 1) | kh) << 14) + boff;
        d[0] = *(const bf16x8*)(p);
        d[1] = *(const bf16x8*)(p + 1024);
        d[2] = *(const bf16x8*)(p + 2048);
        d[3] = *(const bf16x8*)(p + 3072);
    };
    auto cluster = [&](const bf16x8* a, const bf16x8* b, int r0) {
        __builtin_amdgcn_s_setprio(1);
#pragma unroll
        for (int i = 0; i < 4; ++i)
#pragma unroll
            for (int n = 0; n < 4; ++n)
                acc[r0 + i][n] = __builtin_amdgcn_mfma_f32_16x16x32_bf16(
                    a[i], b[n], acc[r0 + i][n], 0, 0, 0);
        __builtin_amdgcn_s_setprio(0);
    };

    // ---- prologue: stage tile 0; kh0 landed, kh1 (4 loads) in flight ----
    issue(0, 0, 0, 0);
    issue(1, 0, 0, 0);
    issue(0, 0, 1, 0);
    issue(1, 0, 1, 0);
    SYNC_VM(4);

    // ---- main loop. Invariant at top: 4 loads in flight (tile t's kh1) ----
    for (int t = 0; t < NT - 1; ++t) {
        const int c = t & 1, o = c ^ 1;
        const int k1 = (t + 1) * BK;
        // half 0: reads issue ahead; MFMA overlaps LDS datapath via fine lgkm
        issue(0, o, 0, k1);
        rdA(c, 0, 0, af0); rdB(c, 0, bf0); rdA(c, 0, 1, af1);
        issue(1, o, 0, k1);
        cluster(af0, bf0, 0);
        cluster(af1, bf0, 4);
        SYNC_VM(4);                  // retire t.kh1; keep (t+1).kh0 in flight
        // half 1
        issue(0, o, 1, k1);
        rdA(c, 1, 0, af0); rdB(c, 1, bf0); rdA(c, 1, 1, af1);
        issue(1, o, 1, k1);
        cluster(af0, bf0, 0);
        cluster(af1, bf0, 4);
        SYNC_VM(4);                  // retire (t+1).kh0; keep (t+1).kh1
    }

    // ---- epilogue tile NT-1 (no prefetch) ----
    {
        const int c = (NT - 1) & 1;
        rdA(c, 0, 0, af0); rdB(c, 0, bf0); rdA(c, 0, 1, af1);
        cluster(af0, bf0, 0);
        cluster(af1, bf0, 4);
        SYNC_VM(0);                  // kh1 slots landed
        rdA(c, 1, 0, af0); rdB(c, 1, bf0); rdA(c, 1, 1, af1);
        cluster(af0, bf0, 0);
        cluster(af1, bf0, 4);
    }

    // ---- C write: col = lane&15, row = (lane>>4)*4 + j ----
    const int lc = lane & 15;
    const int lr4 = (lane >> 4) * 4;
    const int nbase0 = bcol * BN + wc * 64 + lc;
    const int mbase0 = brow * BM + wr * 128 + lr4;
#pragma unroll
    for (int ni = 0; ni < 4; ++ni) {
        const int n = nbase0 + ni * 16;
        const float s  = scales[n];
        const float bz = bias[n];
#pragma unroll
        for (int mi = 0; mi < 8; ++mi) {
            const int mb = mbase0 + mi * 16;
#pragma unroll
            for (int j = 0; j < 4; ++j) {
                C[(size_t)(mb + j) * N + n] = fmaf(acc[mi][ni][j], s, bz);
            }
        }
    }
}

// ---- Fallback: plain fp32 tiled GEMM, correctness insurance ----------------
__global__ void qlinear_fallback(const float* __restrict__ A,
                                 const float* __restrict__ B,
                                 const float* __restrict__ scales,
                                 const float* __restrict__ bias,
                                 float* __restrict__ C, int M, int N, int K) {
    __shared__ float As[16][17], Bs[16][17];
    const int tx = threadIdx.x, ty = threadIdx.y;
    const int row = blockIdx.y * 16 + ty;
    const int col = blockIdx.x * 16 + tx;
    float acc = 0.f;
    for (int k0 = 0; k0 < K; k0 += 16) {
        As[ty][tx] = A[(long)row * K + k0 + tx];
        Bs[ty][tx] = B[(long)(blockIdx.x * 16 + ty) * K + k0 + tx];
        __syncthreads();
#pragma unroll
        for (int kk = 0; kk < 16; ++kk) acc += As[ty][kk] * Bs[tx][kk];
        __syncthreads();
    }
    C[(long)row * N + col] = fmaf(acc, scales[col], bias[col]);
}

extern "C" void kernel_launch(void* const* d_in, const int* in_sizes, int n_in,
                              void* d_out, int out_size, void* d_ws, size_t ws_size,
                              hipStream_t stream) {
    const float* x      = (const float*)d_in[0];
    const float* w      = (const float*)d_in[1];
    const float* scales = (const float*)d_in[2];
    const float* bias   = (const float*)d_in[3];
    float* out = (float*)d_out;

    const int N = in_sizes[2];                  // 11008
    const int K = (int)((long)in_sizes[1] / N); // 4096
    const int M = (int)((long)in_sizes[0] / K); // 4096

    const size_t need = ((size_t)M * K + (size_t)N * K) * sizeof(unsigned short);
    const bool ws_ok = (ws_size >= need);

    if (ws_ok && (M % 256) == 0 && (N % 256) == 0 && (K % 64) == 0 && (K / 64) >= 2) {
        unsigned short* xb = (unsigned short*)d_ws;
        unsigned short* wb = xb + (size_t)M * K;
        f32_to_bf16_kernel<<<2048, 256, 0, stream>>>(x, (unsigned int*)xb, (long)M * K / 8);
        f32_to_bf16_kernel<<<2048, 256, 0, stream>>>(w, (unsigned int*)wb, (long)N * K / 8);
        const int nbx = N / 256;
        const int nwg = nbx * (M / 256);
        qlinear_gemm_v3<<<nwg, 512, 0, stream>>>(xb, wb, scales, bias, out, M, N, K, nbx);
    } else {
        dim3 grid(N / 16, M / 16), blk(16, 16);
        qlinear_fallback<<<grid, blk, 0, stream>>>(x, w, scales, bias, out, M, N, K);
    }
}

// Round 4
// 417.658 us; speedup vs baseline: 1.3230x; 1.0696x over previous
//
#include <hip/hip_runtime.h>
#include <hip/hip_bf16.h>

// ---------------------------------------------------------------------------
// QuantizedLinear: out[M,N] = (x[M,K] @ (Wq[N,K]*s[N,1]).T) + b[N]
// Wq int8-valued -> bf16 EXACT; x -> bf16 RNE. bf16 MFMA GEMM, scale+bias in
// fp32 epilogue. M=4096 K=4096 N=11008.
// Round 4: full m201-style schedule. 4 phases/K-tile = C-quadrants with
// split-half fragment mapping (mi0-3 -> A-half0, mi4-7 -> A-half1, ni0-1 ->
// B-half0, ni2-3 -> B-half1), reads 12/8/4/0 per phase (register-cached),
// mid-tile LDS region recycling -> 3 half-tiles prefetch, vmcnt(6) once per
// tile. Swizzle: 16B-chunk ^= (row&7) on 128B rows (2 lanes/bank).
// ---------------------------------------------------------------------------

typedef __attribute__((ext_vector_type(8))) short bf16x8;   // 8 bf16 = 4 VGPR
typedef __attribute__((ext_vector_type(4))) float f32x4;
typedef __attribute__((ext_vector_type(4))) unsigned int u32x4;

// ---- fp32 -> bf16 (round-to-nearest-even), 8 elems/thread/iter -------------
__device__ static inline unsigned int bf16rn(unsigned int u) {
    return (u + 0x7FFFu + ((u >> 16) & 1u)) >> 16;
}
__device__ static inline unsigned int pack2(unsigned int lo, unsigned int hi) {
    return bf16rn(lo) | (bf16rn(hi) << 16);
}

// one kernel converts both x and w (fewer launches)
__global__ void f32_to_bf16_both(const float* __restrict__ inx,
                                 unsigned int* __restrict__ outx, long n8x,
                                 const float* __restrict__ inw,
                                 unsigned int* __restrict__ outw, long n8tot) {
    const long stride = (long)gridDim.x * blockDim.x;
    for (long i = (long)blockIdx.x * blockDim.x + threadIdx.x; i < n8tot; i += stride) {
        const float* in; unsigned int* out; long j;
        if (i < n8x) { in = inx; out = outx; j = i; }
        else         { in = inw; out = outw; j = i - n8x; }
        u32x4 a = reinterpret_cast<const u32x4*>(in)[j * 2];
        u32x4 b = reinterpret_cast<const u32x4*>(in)[j * 2 + 1];
        u32x4 o;
        o.x = pack2(a.x, a.y);
        o.y = pack2(a.z, a.w);
        o.z = pack2(b.x, b.y);
        o.w = pack2(b.z, b.w);
        reinterpret_cast<u32x4*>(out)[j] = o;
    }
}

// ---------------------------------------------------------------------------
// 256x256x64 GEMM, 512 threads (8 waves, 2M x 4N), per-wave C = 128x64.
// LDS 128 KiB = 8 regions of 16 KiB: addr = (mat<<16)|(dbuf<<15)|(half<<14),
// region = 128 rows x 64 bf16 (128 B rows). A-half h = tile rows [h*128,+128);
// B-half h = tile cols [h*128,+128).
// ---------------------------------------------------------------------------
#define BK 64

#define GLOAD16(src, dst) __builtin_amdgcn_global_load_lds( \
    (const __attribute__((address_space(1))) void*)(src),   \
    (__attribute__((address_space(3))) void*)(dst), 16, 0, 0)

#define FENCE() asm volatile("" ::: "memory")
#define BAR()  do { FENCE(); __builtin_amdgcn_s_barrier(); FENCE(); } while (0)
#define WAIT_VM(n) asm volatile("s_waitcnt vmcnt(" #n ")" ::: "memory")
#define PACE_LGKM(n) asm volatile("s_waitcnt lgkmcnt(" #n ")" ::: "memory")

__global__ __launch_bounds__(512, 2)
void qlinear_gemm_v4(const unsigned short* __restrict__ A,  // [M,K] bf16
                     const unsigned short* __restrict__ B,  // [N,K] bf16
                     const float* __restrict__ scales,
                     const float* __restrict__ bias,
                     float* __restrict__ C,                 // [M,N] f32
                     int M, int N, int K, int nbx) {
    __shared__ __align__(128) char smem[131072];

    const int tid  = threadIdx.x;
    const int lane = tid & 63;
    const int wid  = tid >> 6;
    const int wr   = wid >> 2;   // 0..1
    const int wc   = wid & 3;    // 0..3

    // T1: bijective XCD swizzle (m204); bcol-fastest for A-panel reuse per XCD
    const int nwg = gridDim.x;
    const int q = nwg >> 3, r = nwg & 7;
    const int xcd = blockIdx.x & 7, boff_ = blockIdx.x >> 3;
    const int swz = (xcd < r ? xcd * (q + 1) : r * (q + 1) + (xcd - r) * q) + boff_;
    const int bcol = swz % nbx;
    const int brow = swz / nbx;

    const unsigned short* Ag = A + (size_t)brow * 256 * K;
    const unsigned short* Bg = B + (size_t)bcol * 256 * K;

    // ---- staging: half-tile (mat,h) = 128 rows x 64 el = 16 KiB,
    // 2 gloads/thread. LDS dest linear (wave*2KiB + lane*16); global source
    // pre-swizzled: k-chunk = (lane&7) ^ (row&7).
    const int sr = lane >> 3;                 // row-within-8
    const int sc = ((lane & 7) ^ sr) << 4;    // source k-chunk bytes
    auto stage = [&](int mat, int d, int h, int t) {
        const unsigned short* G = mat ? Bg : Ag;
        const char* g0 = (const char*)G +
            ((size_t)(h * 128 + wid * 16 + sr) * K + t * BK) * 2 + sc;
        char* l0 = smem + ((mat << 16) | (d << 15) | (h << 14)) +
                   wid * 2048 + lane * 16;
        GLOAD16(g0, l0);
        GLOAD16(g0 + (size_t)8 * K * 2, l0 + 1024);   // +8 rows
    };

    // ---- reads: frag (row16-block, kk): lane -> row base+(lane&15),
    // phys chunk = (kk*4 + (lane>>4)) ^ (lane&7). 2 lanes/bank.
    const int lA  = (lane & 15) * 128;
    const int lx0 = ((0 + (lane >> 4)) ^ (lane & 7)) << 4;   // kk=0
    const int lx1 = ((4 + (lane >> 4)) ^ (lane & 7)) << 4;   // kk=1
    auto rdA = [&](int c, int h, bf16x8 (&d)[4][2]) {        // 8 ds_read_b128
        const char* p = smem + ((c << 15) | (h << 14)) + wr * 8192 + lA;
#pragma unroll
        for (int m = 0; m < 4; ++m) {
            d[m][0] = *(const bf16x8*)(p + m * 2048 + lx0);
            d[m][1] = *(const bf16x8*)(p + m * 2048 + lx1);
        }
    };
    auto rdB = [&](int c, int h, bf16x8 (&d)[2][2]) {        // 4 ds_read_b128
        const char* p = smem + ((1 << 16) | (c << 15) | (h << 14)) + wc * 4096 + lA;
#pragma unroll
        for (int n = 0; n < 2; ++n) {
            d[n][0] = *(const bf16x8*)(p + n * 2048 + lx0);
            d[n][1] = *(const bf16x8*)(p + n * 2048 + lx1);
        }
    };

    f32x4 acc[8][4] = {};
    bf16x8 af0[4][2], af1[4][2], bfr[2][2];

    auto quad = [&](bf16x8 (&a)[4][2], bf16x8 (&b)[2][2], int qm, int qn) {
        __builtin_amdgcn_s_setprio(1);
#pragma unroll
        for (int i = 0; i < 4; ++i)
#pragma unroll
            for (int nn = 0; nn < 2; ++nn)
#pragma unroll
                for (int kk = 0; kk < 2; ++kk)
                    acc[qm * 4 + i][qn * 2 + nn] =
                        __builtin_amdgcn_mfma_f32_16x16x32_bf16(
                            a[i][kk], b[nn][kk], acc[qm * 4 + i][qn * 2 + nn], 0, 0, 0);
        __builtin_amdgcn_s_setprio(0);
    };

    const int NT = K / BK;

    // ---- prologue: t0 all 4 half-tiles, then t1's first 3 ----
    stage(0, 0, 0, 0); stage(1, 0, 0, 0); stage(0, 0, 1, 0); stage(1, 0, 1, 0);
    WAIT_VM(4);
    if (NT > 1) {
        stage(0, 1, 0, 1); stage(1, 1, 0, 1); stage(0, 1, 1, 1);
        WAIT_VM(6);
    } else {
        WAIT_VM(0);
    }
    BAR();

    // ---- main loop: invariant at top: t landed; t+1:{A0,B0,A1} in flight ----
    for (int t = 0; t < NT; ++t) {
        const int c = t & 1, o = c ^ 1;
        const bool s1 = (t + 1 < NT), s2 = (t + 2 < NT);
        // P1: quad(0,0) | reads A0(8)+B0(4) | stage t+1:B1
        rdA(c, 0, af0); rdB(c, 0, bfr);
        if (s1) stage(1, o, 1, t + 1);
        PACE_LGKM(8);
        BAR();
        quad(af0, bfr, 0, 0);
        BAR();
        // P2: quad(1,0) | reads A1(8) | stage t+2:A0 (region freed after P1)
        rdA(c, 1, af1);
        if (s2) stage(0, c, 0, t + 2);
        BAR();
        quad(af1, bfr, 1, 0);
        BAR();
        // P3: quad(0,1) | reads B1(4) | stage t+2:B0 (freed after P1)
        rdB(c, 1, bfr);
        if (s2) stage(1, c, 0, t + 2);
        BAR();
        quad(af0, bfr, 0, 1);
        BAR();
        // P4: quad(1,1) | stage t+2:A1 (freed after P2) | single vm wait
        if (s2) stage(0, c, 1, t + 2);
        quad(af1, bfr, 1, 1);
        if (s2)      { WAIT_VM(6); }   // retires exactly tile t+1
        else if (s1) { WAIT_VM(0); }
        BAR();
    }

    // ---- C write: row(mi) = (mi>>2)*128 + wr*64 + (mi&3)*16 + (lane>>4)*4+j
    //              col(ni) = (ni>>1)*128 + wc*32 + (ni&1)*16 + (lane&15)
    const int lc  = lane & 15;
    const int lr4 = (lane >> 4) * 4;
#pragma unroll
    for (int ni = 0; ni < 4; ++ni) {
        const int n = bcol * 256 + (ni >> 1) * 128 + wc * 32 + (ni & 1) * 16 + lc;
        const float s  = scales[n];
        const float bz = bias[n];
#pragma unroll
        for (int mi = 0; mi < 8; ++mi) {
            const int mb = brow * 256 + (mi >> 2) * 128 + wr * 64 + (mi & 3) * 16 + lr4;
#pragma unroll
            for (int j = 0; j < 4; ++j) {
                C[(size_t)(mb + j) * N + n] = fmaf(acc[mi][ni][j], s, bz);
            }
        }
    }
}

// ---- Fallback: plain fp32 tiled GEMM, correctness insurance ----------------
__global__ void qlinear_fallback(const float* __restrict__ A,
                                 const float* __restrict__ B,
                                 const float* __restrict__ scales,
                                 const float* __restrict__ bias,
                                 float* __restrict__ C, int M, int N, int K) {
    __shared__ float As[16][17], Bs[16][17];
    const int tx = threadIdx.x, ty = threadIdx.y;
    const int row = blockIdx.y * 16 + ty;
    const int col = blockIdx.x * 16 + tx;
    float acc = 0.f;
    for (int k0 = 0; k0 < K; k0 += 16) {
        As[ty][tx] = A[(long)row * K + k0 + tx];
        Bs[ty][tx] = B[(long)(blockIdx.x * 16 + ty) * K + k0 + tx];
        __syncthreads();
#pragma unroll
        for (int kk = 0; kk < 16; ++kk) acc += As[ty][kk] * Bs[tx][kk];
        __syncthreads();
    }
    C[(long)row * N + col] = fmaf(acc, scales[col], bias[col]);
}

extern "C" void kernel_launch(void* const* d_in, const int* in_sizes, int n_in,
                              void* d_out, int out_size, void* d_ws, size_t ws_size,
                              hipStream_t stream) {
    const float* x      = (const float*)d_in[0];
    const float* w      = (const float*)d_in[1];
    const float* scales = (const float*)d_in[2];
    const float* bias   = (const float*)d_in[3];
    float* out = (float*)d_out;

    const int N = in_sizes[2];                  // 11008
    const int K = (int)((long)in_sizes[1] / N); // 4096
    const int M = (int)((long)in_sizes[0] / K); // 4096

    const size_t need = ((size_t)M * K + (size_t)N * K) * sizeof(unsigned short);
    const bool ws_ok = (ws_size >= need);

    if (ws_ok && (M % 256) == 0 && (N % 256) == 0 && (K % 64) == 0 && (K / 64) >= 2) {
        unsigned short* xb = (unsigned short*)d_ws;
        unsigned short* wb = xb + (size_t)M * K;
        const long n8x = (long)M * K / 8;
        const long n8t = n8x + (long)N * K / 8;
        f32_to_bf16_both<<<2048, 256, 0, stream>>>(x, (unsigned int*)xb, n8x,
                                                   w, (unsigned int*)wb, n8t);
        const int nbx = N / 256;
        const int nwg = nbx * (M / 256);
        qlinear_gemm_v4<<<nwg, 512, 0, stream>>>(xb, wb, scales, bias, out, M, N, K, nbx);
    } else {
        dim3 grid(N / 16, M / 16), blk(16, 16);
        qlinear_fallback<<<grid, blk, 0, stream>>>(x, w, scales, bias, out, M, N, K);
    }
}